// Round 4
// baseline (435.810 us; speedup 1.0000x reference)
//
#include <hip/hip_runtime.h>
#include <cstdint>

#define B_ 16
#define H_ 224
#define W_ 224
#define C_ 32
#define HW_ (H_*W_)            // 50176

__device__ __forceinline__ unsigned int enc_f32(float f) {
    unsigned int u = __float_as_uint(f);
    return (u & 0x80000000u) ? ~u : (u | 0x80000000u);
}
__device__ __forceinline__ float dec_f32(unsigned int u) {
    unsigned int v = (u & 0x80000000u) ? (u & 0x7fffffffu) : ~u;
    return __uint_as_float(v);
}

__global__ void k_init(unsigned int* scratch) {
    int t = threadIdx.x;
    if (t < B_) { scratch[t] = 0xFFFFFFFFu; scratch[B_ + t] = 0u; }
}

// K1 v2: pure streaming per-sample min/max over NHWC x (no transpose).
__global__ __launch_bounds__(256) void k_minmax(
        const float* __restrict__ x, unsigned int* __restrict__ scratch) {
    __shared__ float rmin[4], rmax[4];
    int t = threadIdx.x;
    int b = blockIdx.y;
    const float4* p = (const float4*)(x + (size_t)b * HW_ * C_);
    const int n4 = HW_ * C_ / 4;   // 401408
    float vmin = 1e30f, vmax = -1e30f;
    for (int i = blockIdx.x * 256 + t; i < n4; i += gridDim.x * 256) {
        float4 v = p[i];
        vmin = fminf(vmin, fminf(fminf(v.x, v.y), fminf(v.z, v.w)));
        vmax = fmaxf(vmax, fmaxf(fmaxf(v.x, v.y), fmaxf(v.z, v.w)));
    }
    for (int off = 32; off; off >>= 1) {
        vmin = fminf(vmin, __shfl_down(vmin, off));
        vmax = fmaxf(vmax, __shfl_down(vmax, off));
    }
    if ((t & 63) == 0) { rmin[t >> 6] = vmin; rmax[t >> 6] = vmax; }
    __syncthreads();
    if (t == 0) {
        atomicMin(&scratch[b],      enc_f32(fminf(fminf(rmin[0], rmin[1]), fminf(rmin[2], rmin[3]))));
        atomicMax(&scratch[B_ + b], enc_f32(fmaxf(fmaxf(rmax[0], rmax[1]), fmaxf(rmax[2], rmax[3]))));
    }
}

// K2 v4: full-line fused kernel, de-risked from v3 (which never benched:
// container failed -- possibly 68.6KB static LDS or ~250-VGPR pressure).
//  - lout single-buffered: LDS 51.5KB (< 64KB static limit).
//    Extra B-sync per iter: A-sync orders prev emits before store-reads;
//    B-sync orders store-reads before this iter's emit-writes.
//  - depth-1 load queue (q0 only): -8 VGPR, one iteration (~300cy) of
//    latency cover + 8 waves of TLP.
// Structure: block = 512 thr = 8 waves owns ALL 32 channels of its pixels
// (full 128B HBM lines both directions -- R2's 8ch blocks cost 2x fetch /
// 1.6x write). Wave wid computes channels wid*4..+3 with the proven v6
// pipeline (2 cols/lane, depth-8 rings); strip of 112 cols (+16 halo),
// chunk of 32 rows (h0%8==0 keeps ring phases compile-time).
// Grid = 16b x 2strip x 7chunk = 224 blocks.
__global__ __launch_bounds__(512, 2) void k_fused(
        const float* __restrict__ x, float* __restrict__ out,
        const float* __restrict__ gamma, const float* __restrict__ beta,
        const float* __restrict__ mmean, const float* __restrict__ mvar,
        const unsigned int* __restrict__ scratch) {
    __shared__ float lin[2][32][134];
    __shared__ float lout[32][134];
    const int t    = threadIdx.x;
    const int wid  = t >> 6;
    const int lane = t & 63;

    int bid   = blockIdx.x;            // (b*2 + strip)*7 + chunk
    int chunk = bid % 7;
    int bs    = bid / 7;
    int strip = bs & 1;
    int b     = bs >> 1;

    const int cch   = wid * 4;         // this wave's first channel
    const int h0    = chunk * 32;      // 0..192, all % 8 == 0
    const int sbase = strip * 112;

    // BN constants (wave-uniform scalar loads)
    float sc[4], bi[4];
    #pragma unroll
    for (int k = 0; k < 4; ++k) {
        float s = gamma[cch + k] * rsqrtf(mvar[cch + k] + 1e-3f);
        sc[k] = s;
        bi[k] = beta[cch + k] - mmean[cch + k] * s;
    }

    float mn   = dec_f32(scratch[b]);
    float mx   = dec_f32(scratch[B_ + b]);
    float inv  = 1.0f / (mx - mn + 1e-7f);
    float minv = mn * inv;

    // pipeline-lane column mapping (identical to v6)
    int c0 = sbase - 8 + 2 * lane;
    int c1 = c0 + 1;
    bool mC = (c0 >= 0) && (c0 <= W_ - 2);

    // loader/storer mapping: 4 threads per pixel cover the full 128B line
    int p    = t >> 2;                         // local col 0..127
    int chb  = (t & 3) * 8;                    // 8 channels per thread
    int gw   = min(max(sbase - 8 + p, 0), W_ - 1);
    int gws  = sbase - 8 + p;
    bool colok = (p >= 8) && (p < 120);
    const float* xb = x   + (size_t)b * HW_ * C_ + chb;
    float*       ob = out + (size_t)b * HW_ * C_ + chb;

    // per-column W-direction valid counts and folded constants
    // (column-dependent, channel-INdependent -> shared across the 4 channels)
    float cw2_0  = (float)(min(c0+1, W_-1) - c0 + 1);
    float cw2_1  = (float)(min(c1+1, W_-1) - c1 + 1);
    float cw4_0  = (float)(min(c0+2, W_-1) - max(c0-1, 0) + 1);
    float cw4_1  = (float)(min(c1+2, W_-1) - max(c1-1, 0) + 1);
    float cw8_0  = (float)(min(c0+4, W_-1) - max(c0-3, 0) + 1);
    float cw8_1  = (float)(min(c1+4, W_-1) - max(c1-3, 0) + 1);
    float cw16_0 = (float)(min(c0+8, W_-1) - max(c0-7, 0) + 1);
    float cw16_1 = (float)(min(c1+8, W_-1) - max(c1-7, 0) + 1);
    float e2_0  = minv * cw2_0,  e2_1  = minv * cw2_1;
    float e4_0  = minv * cw4_0,  e4_1  = minv * cw4_1;
    float e8_0  = minv * cw8_0,  e8_1  = minv * cw8_1;
    float e16_0 = minv * cw16_0, e16_1 = minv * cw16_1;
    float d2_0  = 1e-7f -  2.0f * e2_0,  d2_1  = 1e-7f -  2.0f * e2_1;
    float d4_0  = 1e-7f -  4.0f * e4_0,  d4_1  = 1e-7f -  4.0f * e4_1;
    float d8_0  = 1e-7f -  8.0f * e8_0,  d8_1  = 1e-7f -  8.0f * e8_1;
    float d16_0 = 1e-7f - 16.0f * e16_0, d16_1 = 1e-7f - 16.0f * e16_1;

    // per-channel pipeline state (all indices compile-time under unroll)
    float hp0[4] = {}, hp1[4] = {};
    float rB4[4][2][2]  = {};
    float rB8[4][2][4]  = {};
    float rB16[4][2][8] = {};
    float acc[4][2][8]  = {};

#define LDR(DA, DB, AR) { int r_ = min(max((AR), 0), H_-1); \
    const float* rp_ = xb + ((size_t)r_ * W_ + gw) * C_; \
    DA = *(const float4*)rp_; DB = *(const float4*)(rp_ + 4); }

    // prologue: stage row h0-7 into lin[1]; preload q0 (row h0-6)
    float4 q0a, q0b;
    {
        float4 ta, tb;
        LDR(ta, tb, h0 - 7);
        lin[1][chb+0][p] = ta.x; lin[1][chb+1][p] = ta.y;
        lin[1][chb+2][p] = ta.z; lin[1][chb+3][p] = ta.w;
        lin[1][chb+4][p] = tb.x; lin[1][chb+5][p] = tb.y;
        lin[1][chb+6][p] = tb.z; lin[1][chb+7][p] = tb.w;
        LDR(q0a, q0b, h0 - 6);
    }

    for (int g8 = 0; g8 < 6; ++g8) {       // 48 iters: 16 warmup + 32 rows
        #pragma unroll
        for (int u = 0; u < 8; ++u) {
            int it = g8 * 8 + u;
            int a  = h0 - 7 + it;          // absolute input row
            __syncthreads();               // A: prev emits done, lin staged
            // read this row (staged last iter) for all 4 channels
            float2 lv[4];
            #pragma unroll
            for (int k = 0; k < 4; ++k)
                lv[k] = *(const float2*)&lin[(u + 1) & 1][cch + k][2 * lane];
            // stage next row a+1 into buffer u&1
            lin[u & 1][chb+0][p] = q0a.x; lin[u & 1][chb+1][p] = q0a.y;
            lin[u & 1][chb+2][p] = q0a.z; lin[u & 1][chb+3][p] = q0a.w;
            lin[u & 1][chb+4][p] = q0b.x; lin[u & 1][chb+5][p] = q0b.y;
            lin[u & 1][chb+6][p] = q0b.z; lin[u & 1][chb+7][p] = q0b.w;
            LDR(q0a, q0b, a + 2);
            // coop full-line store of the row emitted LAST iter
            if (it >= 16 && colok) {
                int op = h0 - 16 + it;
                float4 sa, sb;
                sa.x = lout[chb+0][p]; sa.y = lout[chb+1][p];
                sa.z = lout[chb+2][p]; sa.w = lout[chb+3][p];
                sb.x = lout[chb+4][p]; sb.y = lout[chb+5][p];
                sb.z = lout[chb+6][p]; sb.w = lout[chb+7][p];
                float* wp = ob + ((size_t)op * W_ + gws) * C_;
                *(float4*)wp = sa; *(float4*)(wp + 4) = sb;
            }
            __syncthreads();               // B: store-reads done before emits

            bool rowok = (a >= 0) && (a < H_);
            bool interior = (a >= 15) && (a <= 223);
            float ch2 = 0.f, ch4 = 0.f, ch8 = 0.f, ch16 = 0.f;
            if (!interior) {
                int o1 = a - 1, o2 = a - 2, o3 = a - 4, o4 = a - 8;
                ch2  = (float)(min(o1+1, H_-1) - o1 + 1);
                ch4  = (float)(min(o2+2, H_-1) - max(o2-1, 0) + 1);
                ch8  = (float)(min(o3+4, H_-1) - max(o3-3, 0) + 1);
                ch16 = (float)(min(o4+8, H_-1) - max(o4-7, 0) + 1);
            }
            bool doemit = (it >= 15 && it <= 46);

            #pragma unroll
            for (int k = 0; k < 4; ++k) {
                float x0 = (rowok && mC) ? lv[k].x : 0.f;
                float x1 = (rowok && mC) ? lv[k].y : 0.f;
                // level 1 H (span 1)
                float nx0 = __shfl_down(x0, 1);
                float xh0 = x0 + x1;
                float xh1 = x1 + nx0;
                // level 1 V -> G2done[a-1]
                float g2_0 = hp0[k] + xh0; hp0[k] = xh0;
                float g2_1 = hp1[k] + xh1; hp1[k] = xh1;
                // level 2 H (span 2)
                float b4n_0 = g2_0 + __shfl_down(g2_0, 1);
                float b4n_1 = g2_1 + __shfl_down(g2_1, 1);
                // level 2 V
                float a4_0 = rB4[k][0][u & 1] + b4n_0; rB4[k][0][u & 1] = b4n_0;
                float a4_1 = rB4[k][1][u & 1] + b4n_1; rB4[k][1][u & 1] = b4n_1;
                // level 3 H (span 4)
                float b8n_0 = a4_0 + __shfl_down(a4_0, 2);
                float b8n_1 = a4_1 + __shfl_down(a4_1, 2);
                // level 3 V
                float a8_0 = rB8[k][0][u & 3] + b8n_0; rB8[k][0][u & 3] = b8n_0;
                float a8_1 = rB8[k][1][u & 3] + b8n_1; rB8[k][1][u & 3] = b8n_1;
                // level 4 H (span 8)
                float b16n_0 = a8_0 + __shfl_down(a8_0, 4);
                float b16n_1 = a8_1 + __shfl_down(a8_1, 4);
                // level 4 V
                float a16_0 = rB16[k][0][u] + b16n_0; rB16[k][0][u] = b16n_0;
                float a16_1 = rB16[k][1][u] + b16n_1; rB16[k][1][u] = b16n_1;
                // realign to output columns (window left-offsets 1/3/7)
                float g4_0  = __shfl_up(a4_1, 1);
                float g4_1  = a4_0;
                float g8_0  = __shfl_up(a8_1, 2);
                float g8_1  = __shfl_up(a8_0, 1);
                float g16_0 = __shfl_up(a16_1, 4);
                float g16_1 = __shfl_up(a16_0, 3);

                float l1_0, l1_1, l2_0, l2_1, l3_0, l3_1, l4_0, l4_1;
                if (interior) {
                    l1_0 = __log2f(fmaxf(fmaf(g2_0,  inv, d2_0 ), 1e-7f));
                    l1_1 = __log2f(fmaxf(fmaf(g2_1,  inv, d2_1 ), 1e-7f));
                    l2_0 = __log2f(fmaxf(fmaf(g4_0,  inv, d4_0 ), 1e-7f));
                    l2_1 = __log2f(fmaxf(fmaf(g4_1,  inv, d4_1 ), 1e-7f));
                    l3_0 = __log2f(fmaxf(fmaf(g8_0,  inv, d8_0 ), 1e-7f));
                    l3_1 = __log2f(fmaxf(fmaf(g8_1,  inv, d8_1 ), 1e-7f));
                    l4_0 = __log2f(fmaxf(fmaf(g16_0, inv, d16_0), 1e-7f));
                    l4_1 = __log2f(fmaxf(fmaf(g16_1, inv, d16_1), 1e-7f));
                } else {
                    l1_0 = __log2f(fmaxf(fmaf(-e2_0,  ch2,  fmaf(g2_0,  inv, 1e-7f)), 1e-7f));
                    l1_1 = __log2f(fmaxf(fmaf(-e2_1,  ch2,  fmaf(g2_1,  inv, 1e-7f)), 1e-7f));
                    l2_0 = __log2f(fmaxf(fmaf(-e4_0,  ch4,  fmaf(g4_0,  inv, 1e-7f)), 1e-7f));
                    l2_1 = __log2f(fmaxf(fmaf(-e4_1,  ch4,  fmaf(g4_1,  inv, 1e-7f)), 1e-7f));
                    l3_0 = __log2f(fmaxf(fmaf(-e8_0,  ch8,  fmaf(g8_0,  inv, 1e-7f)), 1e-7f));
                    l3_1 = __log2f(fmaxf(fmaf(-e8_1,  ch8,  fmaf(g8_1,  inv, 1e-7f)), 1e-7f));
                    l4_0 = __log2f(fmaxf(fmaf(-e16_0, ch16, fmaf(g16_0, inv, 1e-7f)), 1e-7f));
                    l4_1 = __log2f(fmaxf(fmaf(-e16_1, ch16, fmaf(g16_1, inv, 1e-7f)), 1e-7f));
                }
                // accumulate into per-out-row slots (all distinct mod 8)
                acc[k][0][u] = -0.3f * l1_0;                   // row a-1: init
                acc[k][1][u] = -0.3f * l1_1;
                acc[k][0][(u+7)&7] = fmaf(-0.1f, l2_0, acc[k][0][(u+7)&7]);
                acc[k][1][(u+7)&7] = fmaf(-0.1f, l2_1, acc[k][1][(u+7)&7]);
                acc[k][0][(u+5)&7] = fmaf( 0.1f, l3_0, acc[k][0][(u+5)&7]);
                acc[k][1][(u+5)&7] = fmaf( 0.1f, l3_1, acc[k][1][(u+5)&7]);
                // emit row o = a-8 -> BN -> out-LDS (single buffer)
                if (doemit) {
                    float al0 = fmaf(0.3f, l4_0, acc[k][0][(u+1)&7]);
                    float al1 = fmaf(0.3f, l4_1, acc[k][1][(u+1)&7]);
                    float2 ev;
                    ev.x = fmaf(sc[k], al0, bi[k]);
                    ev.y = fmaf(sc[k], al1, bi[k]);
                    *(float2*)&lout[cch + k][2 * lane] = ev;
                }
            }
        }
    }
#undef LDR
}

extern "C" void kernel_launch(void* const* d_in, const int* in_sizes, int n_in,
                              void* d_out, int out_size, void* d_ws, size_t ws_size,
                              hipStream_t stream) {
    const float* x     = (const float*)d_in[0];
    const float* gamma = (const float*)d_in[1];
    const float* beta  = (const float*)d_in[2];
    const float* mmean = (const float*)d_in[3];
    const float* mvar  = (const float*)d_in[4];
    float* out = (float*)d_out;

    unsigned int* scratch = (unsigned int*)d_ws;  // 32 uints

    k_init<<<1, 64, 0, stream>>>(scratch);
    k_minmax<<<dim3(128, B_), 256, 0, stream>>>(x, scratch);
    k_fused<<<224, 512, 0, stream>>>(x, out, gamma, beta, mmean, mvar, scratch);
}

// Round 5
// 275.969 us; speedup vs baseline: 1.5792x; 1.5792x over previous
//
#include <hip/hip_runtime.h>
#include <cstdint>

#define B_ 16
#define H_ 224
#define W_ 224
#define C_ 32
#define HW_ (H_*W_)            // 50176

__device__ __forceinline__ unsigned int enc_f32(float f) {
    unsigned int u = __float_as_uint(f);
    return (u & 0x80000000u) ? ~u : (u | 0x80000000u);
}
__device__ __forceinline__ float dec_f32(unsigned int u) {
    unsigned int v = (u & 0x80000000u) ? (u & 0x7fffffffu) : ~u;
    return __uint_as_float(v);
}

__global__ void k_init(unsigned int* scratch) {
    int t = threadIdx.x;
    if (t < B_) { scratch[t] = 0xFFFFFFFFu; scratch[B_ + t] = 0u; }
}

// K1 v2: pure streaming per-sample min/max over NHWC x (no transpose).
__global__ __launch_bounds__(256) void k_minmax(
        const float* __restrict__ x, unsigned int* __restrict__ scratch) {
    __shared__ float rmin[4], rmax[4];
    int t = threadIdx.x;
    int b = blockIdx.y;
    const float4* p = (const float4*)(x + (size_t)b * HW_ * C_);
    const int n4 = HW_ * C_ / 4;   // 401408
    float vmin = 1e30f, vmax = -1e30f;
    for (int i = blockIdx.x * 256 + t; i < n4; i += gridDim.x * 256) {
        float4 v = p[i];
        vmin = fminf(vmin, fminf(fminf(v.x, v.y), fminf(v.z, v.w)));
        vmax = fmaxf(vmax, fmaxf(fmaxf(v.x, v.y), fmaxf(v.z, v.w)));
    }
    for (int off = 32; off; off >>= 1) {
        vmin = fminf(vmin, __shfl_down(vmin, off));
        vmax = fmaxf(vmax, __shfl_down(vmax, off));
    }
    if ((t & 63) == 0) { rmin[t >> 6] = vmin; rmax[t >> 6] = vmax; }
    __syncthreads();
    if (t == 0) {
        atomicMin(&scratch[b],      enc_f32(fminf(fminf(rmin[0], rmin[1]), fminf(rmin[2], rmin[3]))));
        atomicMax(&scratch[B_ + b], enc_f32(fmaxf(fmaxf(rmax[0], rmax[1]), fmaxf(rmax[2], rmax[3]))));
    }
}

// K2 v5: R2's proven fused kernel (1 ch/wave, 46-float state, VGPR 64, no
// spill) with the ONLY change being HBM request granularity:
//   16 channels per block (1024 thr = 16 waves) instead of 8.
// Per-pixel global access = 16ch x 4B = 64B = one full HBM sector, so the
// R2 amplification (FETCH 2.0x, WRITE 1.6x from 32B sub-sector requests)
// goes to ~1.0x. R4's lesson applied: per-thread state stays at R2's 46
// floats -- the 4ch/wave variant spilled ~290MB of scratch to HBM at
// VGPR=128 and ran 2x SLOWER. launch_bounds(1024,4) caps VGPR at 128
// (body needs ~64): zero spill risk, 16 waves/CU.
// Grid = 16b x 2cg x 2strip x 4chunk(56 rows) = 256 blocks (1 per CU).
__global__ __launch_bounds__(1024, 4) void k_fused(
        const float* __restrict__ x, float* __restrict__ out,
        const float* __restrict__ gamma, const float* __restrict__ beta,
        const float* __restrict__ mmean, const float* __restrict__ mvar,
        const unsigned int* __restrict__ scratch) {
    __shared__ float lin[2][16][132];
    __shared__ float lout[2][16][132];
    const int t    = threadIdx.x;
    const int wid  = t >> 6;               // 0..15: channel within group
    const int lane = t & 63;

    int bid   = blockIdx.x;                // ((b*4 + chunk)*2 + strip)*2 + cg
    int cg    = bid & 1;
    int strip = (bid >> 1) & 1;
    int chunk = (bid >> 2) & 3;
    int b     = bid >> 4;

    const int cbase = cg * 16;
    const int c     = cbase + wid;         // this wave's channel
    const int h0    = chunk * 56;          // 56 % 8 == 0: ring phases intact
    const int sbase = strip * 112;

    // BN constants (wave-uniform)
    float sc = gamma[c] * rsqrtf(mvar[c] + 1e-3f);
    float bi = beta[c] - mmean[c] * sc;

    float mn   = dec_f32(scratch[b]);
    float mx   = dec_f32(scratch[B_ + b]);
    float inv  = 1.0f / (mx - mn + 1e-7f);
    float minv = mn * inv;

    // pipeline-lane column mapping (identical to R2/v6)
    int c0 = sbase - 8 + 2 * lane;
    int c1 = c0 + 1;
    bool mC = (c0 >= 0) && (c0 <= W_ - 2);

    // loader/storer mapping: 8 threads per pixel cover a 64B half-line
    int col_l = t >> 3;                    // 0..127
    int lch   = (t & 7) * 2;               // 0,2,...,14
    int wld   = min(max(sbase - 8 + col_l, 0), W_ - 1);
    int wst   = sbase - 8 + col_l;         // valid when colok
    bool colok = (col_l >= 8) && (col_l < 120);
    const float* xb = x   + (size_t)b * HW_ * C_ + cbase + lch;
    float*       ob = out + (size_t)b * HW_ * C_ + cbase + lch;

    // per-column W-direction valid counts and folded constants (as R2)
    float cw2_0  = (float)(min(c0+1, W_-1) - c0 + 1);
    float cw2_1  = (float)(min(c1+1, W_-1) - c1 + 1);
    float cw4_0  = (float)(min(c0+2, W_-1) - max(c0-1, 0) + 1);
    float cw4_1  = (float)(min(c1+2, W_-1) - max(c1-1, 0) + 1);
    float cw8_0  = (float)(min(c0+4, W_-1) - max(c0-3, 0) + 1);
    float cw8_1  = (float)(min(c1+4, W_-1) - max(c1-3, 0) + 1);
    float cw16_0 = (float)(min(c0+8, W_-1) - max(c0-7, 0) + 1);
    float cw16_1 = (float)(min(c1+8, W_-1) - max(c1-7, 0) + 1);
    float e2_0  = minv * cw2_0,  e2_1  = minv * cw2_1;
    float e4_0  = minv * cw4_0,  e4_1  = minv * cw4_1;
    float e8_0  = minv * cw8_0,  e8_1  = minv * cw8_1;
    float e16_0 = minv * cw16_0, e16_1 = minv * cw16_1;
    float d2_0  = 1e-7f -  2.0f * e2_0,  d2_1  = 1e-7f -  2.0f * e2_1;
    float d4_0  = 1e-7f -  4.0f * e4_0,  d4_1  = 1e-7f -  4.0f * e4_1;
    float d8_0  = 1e-7f -  8.0f * e8_0,  d8_1  = 1e-7f -  8.0f * e8_1;
    float d16_0 = 1e-7f - 16.0f * e16_0, d16_1 = 1e-7f - 16.0f * e16_1;

    float hp0 = 0.f, hp1 = 0.f;            // Xh[a-1]
    float rB4[2][2]  = {};                 // delay-2
    float rB8[2][4]  = {};                 // delay-4
    float rB16[2][8] = {};                 // delay-8
    float acc[2][8]  = {};                 // alpha partials, slot = out_row & 7

#define LDROW(AR) (*(const float2*)(xb + (size_t)((min(max((AR), 0), H_-1)) * W_ + wld) * C_))

    // prologue: stage row h0-7 into lin[1] (read by it=0); preload q0,q1
    float2 q0, q1;
    {
        float2 qi = LDROW(h0 - 7);
        lin[1][lch][col_l]     = qi.x;
        lin[1][lch + 1][col_l] = qi.y;
        q0 = LDROW(h0 - 6);
        q1 = LDROW(h0 - 5);
    }

    for (int g8 = 0; g8 < 9; ++g8) {       // 72 iters: 16 warmup + 56 rows
        #pragma unroll
        for (int u = 0; u < 8; ++u) {
            int it = g8 * 8 + u;
            int a  = h0 - 7 + it;          // absolute input row
            __syncthreads();
            // this row (staged last iter): buffer (u+1)&1
            float2 lv = *(const float2*)&lin[(u + 1) & 1][wid][2 * lane];
            // stage next row a+1 into buffer u&1
            lin[u & 1][lch][col_l]     = q0.x;
            lin[u & 1][lch + 1][col_l] = q0.y;
            q0 = q1;
            q1 = LDROW(a + 3);
            // coop 64B store of the row emitted LAST iter (from lout[u&1])
            if (it >= 16 && colok) {
                int op = h0 - 16 + it;
                float2 sv;
                sv.x = lout[u & 1][lch][col_l];
                sv.y = lout[u & 1][lch + 1][col_l];
                *(float2*)(ob + (size_t)(op * W_ + wst) * C_) = sv;
            }

            bool rowok = (a >= 0) && (a < H_);
            float x0 = (rowok && mC) ? lv.x : 0.f;
            float x1 = (rowok && mC) ? lv.y : 0.f;
            // level 1 H (span 1)
            float nx0 = __shfl_down(x0, 1);
            float xh0 = x0 + x1;
            float xh1 = x1 + nx0;
            // level 1 V -> G2done[a-1]
            float g2_0 = hp0 + xh0; hp0 = xh0;
            float g2_1 = hp1 + xh1; hp1 = xh1;
            // level 2 H (span 2)
            float b4n_0 = g2_0 + __shfl_down(g2_0, 1);
            float b4n_1 = g2_1 + __shfl_down(g2_1, 1);
            // level 2 V
            float a4_0 = rB4[0][u & 1] + b4n_0; rB4[0][u & 1] = b4n_0;
            float a4_1 = rB4[1][u & 1] + b4n_1; rB4[1][u & 1] = b4n_1;
            // level 3 H (span 4)
            float b8n_0 = a4_0 + __shfl_down(a4_0, 2);
            float b8n_1 = a4_1 + __shfl_down(a4_1, 2);
            // level 3 V
            float a8_0 = rB8[0][u & 3] + b8n_0; rB8[0][u & 3] = b8n_0;
            float a8_1 = rB8[1][u & 3] + b8n_1; rB8[1][u & 3] = b8n_1;
            // level 4 H (span 8)
            float b16n_0 = a8_0 + __shfl_down(a8_0, 4);
            float b16n_1 = a8_1 + __shfl_down(a8_1, 4);
            // level 4 V
            float a16_0 = rB16[0][u] + b16n_0; rB16[0][u] = b16n_0;
            float a16_1 = rB16[1][u] + b16n_1; rB16[1][u] = b16n_1;
            // realign to output columns (window left-offsets 1/3/7)
            float g4_0  = __shfl_up(a4_1, 1);
            float g4_1  = a4_0;
            float g8_0  = __shfl_up(a8_1, 2);
            float g8_1  = __shfl_up(a8_0, 1);
            float g16_0 = __shfl_up(a16_1, 4);
            float g16_1 = __shfl_up(a16_0, 3);

            float l1_0, l1_1, l2_0, l2_1, l3_0, l3_1, l4_0, l4_1;
            if (a >= 15 && a <= 223) {     // all 4 row-counts unclamped
                l1_0 = __log2f(fmaxf(fmaf(g2_0,  inv, d2_0 ), 1e-7f));
                l1_1 = __log2f(fmaxf(fmaf(g2_1,  inv, d2_1 ), 1e-7f));
                l2_0 = __log2f(fmaxf(fmaf(g4_0,  inv, d4_0 ), 1e-7f));
                l2_1 = __log2f(fmaxf(fmaf(g4_1,  inv, d4_1 ), 1e-7f));
                l3_0 = __log2f(fmaxf(fmaf(g8_0,  inv, d8_0 ), 1e-7f));
                l3_1 = __log2f(fmaxf(fmaf(g8_1,  inv, d8_1 ), 1e-7f));
                l4_0 = __log2f(fmaxf(fmaf(g16_0, inv, d16_0), 1e-7f));
                l4_1 = __log2f(fmaxf(fmaf(g16_1, inv, d16_1), 1e-7f));
            } else {
                int o1 = a - 1, o2 = a - 2, o3 = a - 4, o4 = a - 8;
                float ch2  = (float)(min(o1+1, H_-1) - o1 + 1);
                float ch4  = (float)(min(o2+2, H_-1) - max(o2-1, 0) + 1);
                float ch8  = (float)(min(o3+4, H_-1) - max(o3-3, 0) + 1);
                float ch16 = (float)(min(o4+8, H_-1) - max(o4-7, 0) + 1);
                l1_0 = __log2f(fmaxf(fmaf(-e2_0,  ch2,  fmaf(g2_0,  inv, 1e-7f)), 1e-7f));
                l1_1 = __log2f(fmaxf(fmaf(-e2_1,  ch2,  fmaf(g2_1,  inv, 1e-7f)), 1e-7f));
                l2_0 = __log2f(fmaxf(fmaf(-e4_0,  ch4,  fmaf(g4_0,  inv, 1e-7f)), 1e-7f));
                l2_1 = __log2f(fmaxf(fmaf(-e4_1,  ch4,  fmaf(g4_1,  inv, 1e-7f)), 1e-7f));
                l3_0 = __log2f(fmaxf(fmaf(-e8_0,  ch8,  fmaf(g8_0,  inv, 1e-7f)), 1e-7f));
                l3_1 = __log2f(fmaxf(fmaf(-e8_1,  ch8,  fmaf(g8_1,  inv, 1e-7f)), 1e-7f));
                l4_0 = __log2f(fmaxf(fmaf(-e16_0, ch16, fmaf(g16_0, inv, 1e-7f)), 1e-7f));
                l4_1 = __log2f(fmaxf(fmaf(-e16_1, ch16, fmaf(g16_1, inv, 1e-7f)), 1e-7f));
            }
            // accumulate into per-out-row slots (all distinct mod 8)
            acc[0][u] = -0.3f * l1_0;                    // row a-1: init
            acc[1][u] = -0.3f * l1_1;
            acc[0][(u+7)&7] = fmaf(-0.1f, l2_0, acc[0][(u+7)&7]);  // row a-2
            acc[1][(u+7)&7] = fmaf(-0.1f, l2_1, acc[1][(u+7)&7]);
            acc[0][(u+5)&7] = fmaf( 0.1f, l3_0, acc[0][(u+5)&7]);  // row a-4
            acc[1][(u+5)&7] = fmaf( 0.1f, l3_1, acc[1][(u+5)&7]);
            // emit row o = a-8 (it in [15,70]) -> BN -> out-LDS buffer (u+1)&1
            if (it >= 15 && it <= 70) {
                float al0 = fmaf(0.3f, l4_0, acc[(0)][(u+1)&7]);
                float al1 = fmaf(0.3f, l4_1, acc[(1)][(u+1)&7]);
                float2 ev;
                ev.x = fmaf(sc, al0, bi);
                ev.y = fmaf(sc, al1, bi);
                *(float2*)&lout[(u + 1) & 1][wid][2 * lane] = ev;
            }
        }
    }
#undef LDROW
}

extern "C" void kernel_launch(void* const* d_in, const int* in_sizes, int n_in,
                              void* d_out, int out_size, void* d_ws, size_t ws_size,
                              hipStream_t stream) {
    const float* x     = (const float*)d_in[0];
    const float* gamma = (const float*)d_in[1];
    const float* beta  = (const float*)d_in[2];
    const float* mmean = (const float*)d_in[3];
    const float* mvar  = (const float*)d_in[4];
    float* out = (float*)d_out;

    unsigned int* scratch = (unsigned int*)d_ws;  // 32 uints

    k_init<<<1, 64, 0, stream>>>(scratch);
    k_minmax<<<dim3(128, B_), 256, 0, stream>>>(x, scratch);
    k_fused<<<256, 1024, 0, stream>>>(x, out, gamma, beta, mmean, mvar, scratch);
}

// Round 6
// 262.510 us; speedup vs baseline: 1.6602x; 1.0513x over previous
//
#include <hip/hip_runtime.h>
#include <cstdint>

#define B_ 16
#define H_ 224
#define W_ 224
#define C_ 32
#define HW_ (H_*W_)            // 50176

__device__ __forceinline__ unsigned int enc_f32(float f) {
    unsigned int u = __float_as_uint(f);
    return (u & 0x80000000u) ? ~u : (u | 0x80000000u);
}
__device__ __forceinline__ float dec_f32(unsigned int u) {
    unsigned int v = (u & 0x80000000u) ? (u & 0x7fffffffu) : ~u;
    return __uint_as_float(v);
}

__global__ void k_init(unsigned int* scratch) {
    int t = threadIdx.x;
    if (t < B_) { scratch[t] = 0xFFFFFFFFu; scratch[B_ + t] = 0u; }
}

// K1 v2: pure streaming per-sample min/max over NHWC x (no transpose).
__global__ __launch_bounds__(256) void k_minmax(
        const float* __restrict__ x, unsigned int* __restrict__ scratch) {
    __shared__ float rmin[4], rmax[4];
    int t = threadIdx.x;
    int b = blockIdx.y;
    const float4* p = (const float4*)(x + (size_t)b * HW_ * C_);
    const int n4 = HW_ * C_ / 4;   // 401408
    float vmin = 1e30f, vmax = -1e30f;
    for (int i = blockIdx.x * 256 + t; i < n4; i += gridDim.x * 256) {
        float4 v = p[i];
        vmin = fminf(vmin, fminf(fminf(v.x, v.y), fminf(v.z, v.w)));
        vmax = fmaxf(vmax, fmaxf(fmaxf(v.x, v.y), fmaxf(v.z, v.w)));
    }
    for (int off = 32; off; off >>= 1) {
        vmin = fminf(vmin, __shfl_down(vmin, off));
        vmax = fmaxf(vmax, __shfl_down(vmax, off));
    }
    if ((t & 63) == 0) { rmin[t >> 6] = vmin; rmax[t >> 6] = vmax; }
    __syncthreads();
    if (t == 0) {
        atomicMin(&scratch[b],      enc_f32(fminf(fminf(rmin[0], rmin[1]), fminf(rmin[2], rmin[3]))));
        atomicMax(&scratch[B_ + b], enc_f32(fmaxf(fmaxf(rmax[0], rmax[1]), fmaxf(rmax[2], rmax[3]))));
    }
}

// K2 v6: v5 (1 ch/wave, 46-float state, VGPR 64, 16ch/block 64B granularity)
// with two changes:
//  (1) epoch-2 barriers: quad-buffered lin[4]/lout[4] indexed by step&3;
//      ONE barrier per 2 rows (37 total vs 72). Store-reads at epoch top
//      read rows emitted last epoch (barrier-separated); staged lin buffers
//      and emit lout buffers are disjoint from the ones read this epoch.
//      LDS resized under the 64KB static limit: lin[4][16][130] (33.3KB,
//      compute/stage ~2-way banks) + lout[4][16][116] (29.7KB, 112 out
//      cols only, ~2-way) = 62.98KB.
//  (2) XCD write pairing: cg = bid>>7, so the two blocks writing the two
//      64B halves of each 128B output line are bid and bid+128 -- same
//      bid%8 -> same XCD under round-robin dispatch -> halves merge in one
//      L2 before writeback. Tests the half-dirty-128B-line theory for the
//      persistent 1.6x WRITE_SIZE (164 vs 103 MB ideal).
// Grid = 256 blocks x 1024 thr (16 waves, 1 block/CU).
__global__ __launch_bounds__(1024, 4) void k_fused(
        const float* __restrict__ x, float* __restrict__ out,
        const float* __restrict__ gamma, const float* __restrict__ beta,
        const float* __restrict__ mmean, const float* __restrict__ mvar,
        const unsigned int* __restrict__ scratch) {
    __shared__ float lin[4][16][130];
    __shared__ float lout[4][16][116];
    const int t    = threadIdx.x;
    const int wid  = t >> 6;               // 0..15: channel within group
    const int lane = t & 63;

    int bid   = blockIdx.x;                // cg*128 + ((b*4+chunk)*2+strip)
    int cg    = bid >> 7;                  // pair blocks p, p+128: same XCD
    int r     = bid & 127;
    int strip = r & 1;
    int chunk = (r >> 1) & 3;
    int b     = r >> 3;

    const int cbase = cg * 16;
    const int c     = cbase + wid;         // this wave's channel
    const int h0    = chunk * 56;          // 56 % 8 == 0: ring phases intact
    const int sbase = strip * 112;

    // BN constants (wave-uniform)
    float sc = gamma[c] * rsqrtf(mvar[c] + 1e-3f);
    float bi = beta[c] - mmean[c] * sc;

    float mn   = dec_f32(scratch[b]);
    float mx   = dec_f32(scratch[B_ + b]);
    float inv  = 1.0f / (mx - mn + 1e-7f);
    float minv = mn * inv;

    // pipeline-lane column mapping (identical to v5)
    int c0 = sbase - 8 + 2 * lane;
    int c1 = c0 + 1;
    bool mC = (c0 >= 0) && (c0 <= W_ - 2);
    bool laneok = (lane >= 4) && (lane <= 59);

    // loader/storer mapping: 8 threads per pixel cover a 64B half-line
    int col_l = t >> 3;                    // 0..127
    int lch   = (t & 7) * 2;               // 0,2,...,14
    int wld   = min(max(sbase - 8 + col_l, 0), W_ - 1);
    int wst   = sbase - 8 + col_l;         // valid when colok
    int cs    = col_l - 8;                 // lout col index, valid when colok
    bool colok = (col_l >= 8) && (col_l < 120);
    const float* xb = x   + (size_t)b * HW_ * C_ + cbase + lch;
    float*       ob = out + (size_t)b * HW_ * C_ + cbase + lch;

    // per-column W-direction valid counts and folded constants (as v5)
    float cw2_0  = (float)(min(c0+1, W_-1) - c0 + 1);
    float cw2_1  = (float)(min(c1+1, W_-1) - c1 + 1);
    float cw4_0  = (float)(min(c0+2, W_-1) - max(c0-1, 0) + 1);
    float cw4_1  = (float)(min(c1+2, W_-1) - max(c1-1, 0) + 1);
    float cw8_0  = (float)(min(c0+4, W_-1) - max(c0-3, 0) + 1);
    float cw8_1  = (float)(min(c1+4, W_-1) - max(c1-3, 0) + 1);
    float cw16_0 = (float)(min(c0+8, W_-1) - max(c0-7, 0) + 1);
    float cw16_1 = (float)(min(c1+8, W_-1) - max(c1-7, 0) + 1);
    float e2_0  = minv * cw2_0,  e2_1  = minv * cw2_1;
    float e4_0  = minv * cw4_0,  e4_1  = minv * cw4_1;
    float e8_0  = minv * cw8_0,  e8_1  = minv * cw8_1;
    float e16_0 = minv * cw16_0, e16_1 = minv * cw16_1;
    float d2_0  = 1e-7f -  2.0f * e2_0,  d2_1  = 1e-7f -  2.0f * e2_1;
    float d4_0  = 1e-7f -  4.0f * e4_0,  d4_1  = 1e-7f -  4.0f * e4_1;
    float d8_0  = 1e-7f -  8.0f * e8_0,  d8_1  = 1e-7f -  8.0f * e8_1;
    float d16_0 = 1e-7f - 16.0f * e16_0, d16_1 = 1e-7f - 16.0f * e16_1;

    float hp0 = 0.f, hp1 = 0.f;            // Xh[a-1]
    float rB4[2][2]  = {};                 // delay-2
    float rB8[2][4]  = {};                 // delay-4
    float rB16[2][8] = {};                 // delay-8
    float acc[2][8]  = {};                 // alpha partials, slot = out_row & 7

#define LDROW(AR) (*(const float2*)(xb + (size_t)((min(max((AR), 0), H_-1)) * W_ + wld) * C_))

// one pipeline step: read row for step U_ from lin[U_&3], update rings,
// emit out-row (it-15+h0) into lout[U_&3]. Identical math to v5.
#define STEP(U_, IT_, A_) do {                                               \
    float2 lv = *(const float2*)&lin[(U_)&3][wid][2*lane];                   \
    bool rowok = ((A_) >= 0) && ((A_) < H_);                                 \
    float x0 = (rowok && mC) ? lv.x : 0.f;                                   \
    float x1 = (rowok && mC) ? lv.y : 0.f;                                   \
    float nx0 = __shfl_down(x0, 1);                                          \
    float xh0 = x0 + x1;                                                     \
    float xh1 = x1 + nx0;                                                    \
    float g2_0 = hp0 + xh0; hp0 = xh0;                                       \
    float g2_1 = hp1 + xh1; hp1 = xh1;                                       \
    float b4n_0 = g2_0 + __shfl_down(g2_0, 1);                               \
    float b4n_1 = g2_1 + __shfl_down(g2_1, 1);                               \
    float a4_0 = rB4[0][(U_)&1] + b4n_0; rB4[0][(U_)&1] = b4n_0;             \
    float a4_1 = rB4[1][(U_)&1] + b4n_1; rB4[1][(U_)&1] = b4n_1;             \
    float b8n_0 = a4_0 + __shfl_down(a4_0, 2);                               \
    float b8n_1 = a4_1 + __shfl_down(a4_1, 2);                               \
    float a8_0 = rB8[0][(U_)&3] + b8n_0; rB8[0][(U_)&3] = b8n_0;             \
    float a8_1 = rB8[1][(U_)&3] + b8n_1; rB8[1][(U_)&3] = b8n_1;             \
    float b16n_0 = a8_0 + __shfl_down(a8_0, 4);                              \
    float b16n_1 = a8_1 + __shfl_down(a8_1, 4);                              \
    float a16_0 = rB16[0][(U_)&7] + b16n_0; rB16[0][(U_)&7] = b16n_0;        \
    float a16_1 = rB16[1][(U_)&7] + b16n_1; rB16[1][(U_)&7] = b16n_1;        \
    float g4_0  = __shfl_up(a4_1, 1);                                        \
    float g4_1  = a4_0;                                                      \
    float g8_0  = __shfl_up(a8_1, 2);                                        \
    float g8_1  = __shfl_up(a8_0, 1);                                        \
    float g16_0 = __shfl_up(a16_1, 4);                                       \
    float g16_1 = __shfl_up(a16_0, 3);                                       \
    float l1_0, l1_1, l2_0, l2_1, l3_0, l3_1, l4_0, l4_1;                    \
    if ((A_) >= 15 && (A_) <= 223) {                                         \
        l1_0 = __log2f(fmaxf(fmaf(g2_0,  inv, d2_0 ), 1e-7f));               \
        l1_1 = __log2f(fmaxf(fmaf(g2_1,  inv, d2_1 ), 1e-7f));               \
        l2_0 = __log2f(fmaxf(fmaf(g4_0,  inv, d4_0 ), 1e-7f));               \
        l2_1 = __log2f(fmaxf(fmaf(g4_1,  inv, d4_1 ), 1e-7f));               \
        l3_0 = __log2f(fmaxf(fmaf(g8_0,  inv, d8_0 ), 1e-7f));               \
        l3_1 = __log2f(fmaxf(fmaf(g8_1,  inv, d8_1 ), 1e-7f));               \
        l4_0 = __log2f(fmaxf(fmaf(g16_0, inv, d16_0), 1e-7f));               \
        l4_1 = __log2f(fmaxf(fmaf(g16_1, inv, d16_1), 1e-7f));               \
    } else {                                                                 \
        int o1 = (A_) - 1, o2 = (A_) - 2, o3 = (A_) - 4, o4 = (A_) - 8;      \
        float ch2  = (float)(min(o1+1, H_-1) - o1 + 1);                      \
        float ch4  = (float)(min(o2+2, H_-1) - max(o2-1, 0) + 1);            \
        float ch8  = (float)(min(o3+4, H_-1) - max(o3-3, 0) + 1);            \
        float ch16 = (float)(min(o4+8, H_-1) - max(o4-7, 0) + 1);            \
        l1_0 = __log2f(fmaxf(fmaf(-e2_0,  ch2,  fmaf(g2_0,  inv, 1e-7f)), 1e-7f)); \
        l1_1 = __log2f(fmaxf(fmaf(-e2_1,  ch2,  fmaf(g2_1,  inv, 1e-7f)), 1e-7f)); \
        l2_0 = __log2f(fmaxf(fmaf(-e4_0,  ch4,  fmaf(g4_0,  inv, 1e-7f)), 1e-7f)); \
        l2_1 = __log2f(fmaxf(fmaf(-e4_1,  ch4,  fmaf(g4_1,  inv, 1e-7f)), 1e-7f)); \
        l3_0 = __log2f(fmaxf(fmaf(-e8_0,  ch8,  fmaf(g8_0,  inv, 1e-7f)), 1e-7f)); \
        l3_1 = __log2f(fmaxf(fmaf(-e8_1,  ch8,  fmaf(g8_1,  inv, 1e-7f)), 1e-7f)); \
        l4_0 = __log2f(fmaxf(fmaf(-e16_0, ch16, fmaf(g16_0, inv, 1e-7f)), 1e-7f)); \
        l4_1 = __log2f(fmaxf(fmaf(-e16_1, ch16, fmaf(g16_1, inv, 1e-7f)), 1e-7f)); \
    }                                                                        \
    acc[0][(U_)&7] = -0.3f * l1_0;                                           \
    acc[1][(U_)&7] = -0.3f * l1_1;                                           \
    acc[0][((U_)+7)&7] = fmaf(-0.1f, l2_0, acc[0][((U_)+7)&7]);              \
    acc[1][((U_)+7)&7] = fmaf(-0.1f, l2_1, acc[1][((U_)+7)&7]);              \
    acc[0][((U_)+5)&7] = fmaf( 0.1f, l3_0, acc[0][((U_)+5)&7]);              \
    acc[1][((U_)+5)&7] = fmaf( 0.1f, l3_1, acc[1][((U_)+5)&7]);              \
    if ((IT_) >= 15 && (IT_) <= 70) {                                        \
        float al0 = fmaf(0.3f, l4_0, acc[0][((U_)+1)&7]);                    \
        float al1 = fmaf(0.3f, l4_1, acc[1][((U_)+1)&7]);                    \
        if (laneok) {                                                        \
            float2 ev;                                                       \
            ev.x = fmaf(sc, al0, bi);                                        \
            ev.y = fmaf(sc, al1, bi);                                        \
            *(float2*)&lout[(U_)&3][wid][2*lane - 8] = ev;                   \
        }                                                                    \
    }                                                                        \
} while (0)

    // prologue: rows for steps 0,1 into lin[0],lin[1]; q0,q1 = rows for 2,3
    float2 q0, q1;
    {
        float2 r0 = LDROW(h0 - 7);
        lin[0][lch][col_l] = r0.x; lin[0][lch + 1][col_l] = r0.y;
        float2 r1 = LDROW(h0 - 6);
        lin[1][lch][col_l] = r1.x; lin[1][lch + 1][col_l] = r1.y;
        q0 = LDROW(h0 - 5);
        q1 = LDROW(h0 - 4);
    }

    for (int g8 = 0; g8 < 9; ++g8) {       // 72 steps = 36 epochs of 2 rows
        #pragma unroll
        for (int ue = 0; ue < 8; ue += 2) {
            int it = g8 * 8 + ue;
            int a  = h0 - 7 + it;          // input row of step `it`
            __syncthreads();               // epoch barrier
            // store rows emitted LAST epoch (steps it-2, it-1)
            if (it >= 18 && colok) {       // j = it-2 (valid j>=15)
                int o = h0 - 17 + it;
                float2 sv;
                sv.x = lout[(ue + 2) & 3][lch][cs];
                sv.y = lout[(ue + 2) & 3][lch + 1][cs];
                *(float2*)(ob + (size_t)(o * W_ + wst) * C_) = sv;
            }
            if (it >= 16 && colok) {       // j = it-1
                int o = h0 - 16 + it;
                float2 sv;
                sv.x = lout[(ue + 3) & 3][lch][cs];
                sv.y = lout[(ue + 3) & 3][lch + 1][cs];
                *(float2*)(ob + (size_t)(o * W_ + wst) * C_) = sv;
            }
            // stage rows for steps it+2, it+3 (loaded last epoch)
            lin[(ue + 2) & 3][lch][col_l]     = q0.x;
            lin[(ue + 2) & 3][lch + 1][col_l] = q0.y;
            lin[(ue + 3) & 3][lch][col_l]     = q1.x;
            lin[(ue + 3) & 3][lch + 1][col_l] = q1.y;
            // issue loads for steps it+4, it+5
            q0 = LDROW(a + 4);
            q1 = LDROW(a + 5);
            // compute the 2 pipeline steps of this epoch
            STEP(ue,     it,     a);
            STEP(ue + 1, it + 1, a + 1);
        }
    }
    // epilogue: row emitted at step 70 (buffer 70&3 = 2), o = h0+55
    __syncthreads();
    if (colok) {
        float2 sv;
        sv.x = lout[2][lch][cs];
        sv.y = lout[2][lch + 1][cs];
        *(float2*)(ob + (size_t)((h0 + 55) * W_ + wst) * C_) = sv;
    }
#undef STEP
#undef LDROW
}

extern "C" void kernel_launch(void* const* d_in, const int* in_sizes, int n_in,
                              void* d_out, int out_size, void* d_ws, size_t ws_size,
                              hipStream_t stream) {
    const float* x     = (const float*)d_in[0];
    const float* gamma = (const float*)d_in[1];
    const float* beta  = (const float*)d_in[2];
    const float* mmean = (const float*)d_in[3];
    const float* mvar  = (const float*)d_in[4];
    float* out = (float*)d_out;

    unsigned int* scratch = (unsigned int*)d_ws;  // 32 uints

    k_init<<<1, 64, 0, stream>>>(scratch);
    k_minmax<<<dim3(128, B_), 256, 0, stream>>>(x, scratch);
    k_fused<<<256, 1024, 0, stream>>>(x, out, gamma, beta, mmean, mvar, scratch);
}